// Round 12
// baseline (15761.441 us; speedup 1.0000x reference)
//
#include <hip/hip_runtime.h>
#include <stdint.h>

typedef unsigned int u32;
typedef unsigned long long u64;
typedef __attribute__((ext_vector_type(8))) short bf16x8;
typedef __attribute__((ext_vector_type(4))) float f32x4;
typedef __attribute__((ext_vector_type(4))) int i32x4;
typedef __attribute__((ext_vector_type(2))) int i32x2;

#define DEV static __device__ __forceinline__

DEV short f2bf(float f){ u32 u=__float_as_uint(f); return (short)((u + 0x7fffu + ((u>>16)&1u))>>16); }
DEV float bf2f(short s){ return __uint_as_float(((u32)(unsigned short)s)<<16); }
DEV float sig_p(float x){ return 1.f/(1.f+expf(-x)); }
DEV float tanh_fast(float x){ float e=__expf(2.f*x); return 1.f-2.f/(e+1.f); }

// agent-scope (LLC) accessors — proven path
DEV u32  cohl4(const u32* p){ return __hip_atomic_load(p, __ATOMIC_RELAXED, __HIP_MEMORY_SCOPE_AGENT); }
DEV void cohs4(u32* p, u32 v){ __hip_atomic_store(p, v, __ATOMIC_RELAXED, __HIP_MEMORY_SCOPE_AGENT); }
DEV void cohs8(void* p, u64 v){ __hip_atomic_store((u64*)p, v, __ATOMIC_RELAXED, __HIP_MEMORY_SCOPE_AGENT); }

// intra-XCD L2 accessors (sc0 = L1-bypass, L2-visible)
DEV void l2st(u32* p, u32 v){
  asm volatile("global_store_dword %0, %1, off sc0" :: "v"(p), "v"(v) : "memory");
}
DEV void l2st8(void* p, u64 v){
  asm volatile("global_store_dwordx2 %0, %1, off sc0" :: "v"(p), "v"(v) : "memory");
}
DEV void l2ld4x8(const u32* p, i32x4* w){
  asm volatile(
    "global_load_dwordx4 %0, %8, off sc0\n\t"
    "global_load_dwordx4 %1, %8, off offset:16 sc0\n\t"
    "global_load_dwordx4 %2, %8, off offset:32 sc0\n\t"
    "global_load_dwordx4 %3, %8, off offset:48 sc0\n\t"
    "global_load_dwordx4 %4, %8, off offset:64 sc0\n\t"
    "global_load_dwordx4 %5, %8, off offset:80 sc0\n\t"
    "global_load_dwordx4 %6, %8, off offset:96 sc0\n\t"
    "global_load_dwordx4 %7, %8, off offset:112 sc0\n\t"
    "s_waitcnt vmcnt(0)"
    : "=&v"(w[0]),"=&v"(w[1]),"=&v"(w[2]),"=&v"(w[3]),
      "=&v"(w[4]),"=&v"(w[5]),"=&v"(w[6]),"=&v"(w[7])
    : "v"(p) : "memory");
}
DEV void l2ld3(const u32* p, u32* g){
  asm volatile(
    "global_load_dword %0, %3, off sc0\n\t"
    "global_load_dword %1, %3, off offset:2048 sc0\n\t"
    "global_load_dword %2, %4, off sc0\n\t"
    "s_waitcnt vmcnt(0)"
    : "=&v"(g[0]), "=&v"(g[1]), "=&v"(g[2])
    : "v"(p), "v"(p + 1024) : "memory");
}

// ---- XCD team formation with single-team election ----
// tc layout: [xcd*16] per-XCD count, [128] arrivals, [144] claim (0 = none, xcd+1 = winner)
DEV int team_role(u32* tc, u32 need, u32 grid){
  __shared__ int roleS;
  if (threadIdx.x == 0){
    u32 xcd;
    asm volatile("s_getreg_b32 %0, hwreg(HW_REG_XCC_ID)" : "=s"(xcd));
    xcd &= 7u;
    u32 rank = __hip_atomic_fetch_add(&tc[xcd*16], 1u, __ATOMIC_RELAXED, __HIP_MEMORY_SCOPE_AGENT);
    __hip_atomic_fetch_add(&tc[128], 1u, __ATOMIC_RELAXED, __HIP_MEMORY_SCOPE_AGENT);
    while (__hip_atomic_load(&tc[128], __ATOMIC_RELAXED, __HIP_MEMORY_SCOPE_AGENT) < grid)
      __builtin_amdgcn_s_sleep(4);
    u32 cnt = __hip_atomic_load(&tc[xcd*16], __ATOMIC_RELAXED, __HIP_MEMORY_SCOPE_AGENT);
    if (cnt >= need){
      u32 exp0 = 0u;
      __hip_atomic_compare_exchange_strong(&tc[144], &exp0, xcd+1u,
        __ATOMIC_RELAXED, __ATOMIC_RELAXED, __HIP_MEMORY_SCOPE_AGENT);
    }
    u32 win;
    while ((win = __hip_atomic_load(&tc[144], __ATOMIC_RELAXED, __HIP_MEMORY_SCOPE_AGENT)) == 0u)
      __builtin_amdgcn_s_sleep(4);
    roleS = (win == xcd+1u && rank < need) ? (int)rank : -1;
  }
  __syncthreads();
  return roleS;
}

// ---------------- convert / transpose kernels ----------------

__global__ void cvt1d(const float* __restrict__ in, short* __restrict__ out, int n){
  int i = blockIdx.x*256 + threadIdx.x;
  if (i < n) out[i] = f2bf(in[i]);
}

// in f32 [R][C] -> out bf16 [Cpad][R]
__global__ void tconv(const float* __restrict__ in, short* __restrict__ out, int R, int C, int Cpad){
  __shared__ float t[32][33];
  int tx = threadIdx.x, ty = threadIdx.y;
  int c0 = blockIdx.x*32, r0 = blockIdx.y*32;
#pragma unroll
  for (int j=0;j<4;++j){
    int r = r0 + ty + 8*j, c = c0 + tx;
    t[ty+8*j][tx] = (c < C) ? in[(size_t)r*C + c] : 0.f;
  }
  __syncthreads();
#pragma unroll
  for (int j=0;j<4;++j){
    int oc = c0 + ty + 8*j;
    out[(size_t)oc*R + r0 + tx] = f2bf(t[tx][ty+8*j]);
  }
}

// batched transpose: in bf16 [NB][Dd][32] -> out bf16 [NB*32][Dd]
__global__ void btrans(const short* __restrict__ in, short* __restrict__ out, int Dd){
  __shared__ short t[32][33];
  int tx = threadIdx.x, ty = threadIdx.y;
  int d0 = blockIdx.x*32, s = blockIdx.y;
#pragma unroll
  for (int j=0;j<4;++j)
    t[ty+8*j][tx] = in[((size_t)s*Dd + d0 + ty + 8*j)*32 + tx];
  __syncthreads();
#pragma unroll
  for (int j=0;j<4;++j)
    out[((size_t)(s*32 + ty + 8*j))*Dd + d0 + tx] = t[tx][ty+8*j];
}

// [s][1536][32] -> [b][1536][128]
__global__ void etrans(const short* __restrict__ in, short* __restrict__ out){
  __shared__ short t[128][33];
  int c = blockIdx.x, tid = threadIdx.x;
#pragma unroll
  for (int i=0;i<16;++i){
    int idx = tid + i*256;
    t[idx>>5][idx&31] = in[((size_t)(idx>>5)*1536 + c)*32 + (idx&31)];
  }
  __syncthreads();
#pragma unroll
  for (int i=0;i<16;++i){
    int idx = tid + i*256;
    out[((size_t)(idx>>7)*1536 + c)*128 + (idx&127)] = t[idx&127][idx>>7];
  }
}

__global__ void embed_k(const int* __restrict__ tok, const float* __restrict__ emb, short* __restrict__ X){
  int row = blockIdx.x;               // (s,b)
  int s = row >> 5, b = row & 31;
  int tv = tok[b*128 + s];
  X[(size_t)row*256 + threadIdx.x] = f2bf(emb[(size_t)tv*256 + threadIdx.x]);
}

// ---------------- MFMA GEMM  C = A[M,K] * BT[Npad][K] ----------------
// MODE 1: out bf16 T-layout [s][Ntot][32], + bias
// MODE 3: out bf16 row-major [M][Nreal], (+bias)
// MODE 4: out bf16 row-major [M][Ntot] logits (+bias, cols >= Nreal get bias 0)
template<int MODE>
__global__ __launch_bounds__(256) void gemm_k(
  const short* __restrict__ A, const short* __restrict__ BT,
  const float* __restrict__ bias, void* __restrict__ outp,
  float* __restrict__ psum, int Nreal, int K, int Ntot)
{
  const int m0 = blockIdx.y * 128, n0 = blockIdx.x * 128;
  const int tid = threadIdx.x, l = tid & 63, wv = tid >> 6;
  const int wm = wv >> 1, wn = wv & 1;
  __shared__ __align__(16) short As[128*64];
  __shared__ __align__(16) short Bs[128*64];
  f32x4 acc[4][4];
#pragma unroll
  for (int i=0;i<4;++i)
#pragma unroll
    for (int j=0;j<4;++j) acc[i][j] = (f32x4){0.f,0.f,0.f,0.f};

  const int nkb = K >> 6;
  for (int kb=0; kb<nkb; ++kb){
#pragma unroll
    for (int i=0;i<4;++i){
      int si = tid + i*256;
      int row = si >> 3, seg = si & 7;
      u32 off = (u32)(row*128 + seg*16) ^ (u32)((row&7)<<4);
      *(i32x4*)((char*)As + off) = *(const i32x4*)(A + (size_t)(m0+row)*K + kb*64 + seg*8);
      *(i32x4*)((char*)Bs + off) = *(const i32x4*)(BT + (size_t)(n0+row)*K + kb*64 + seg*8);
    }
    __syncthreads();
#pragma unroll
    for (int kt=0; kt<2; ++kt){
      bf16x8 af[4], bfv[4];
      int seg = kt*4 + (l>>4);
#pragma unroll
      for (int f=0; f<4; ++f){
        int ra = wm*64 + f*16 + (l&15);
        af[f]  = *(const bf16x8*)((char*)As + (((u32)(ra*128 + seg*16)) ^ ((u32)(ra&7)<<4)));
        int rb = wn*64 + f*16 + (l&15);
        bfv[f] = *(const bf16x8*)((char*)Bs + (((u32)(rb*128 + seg*16)) ^ ((u32)(rb&7)<<4)));
      }
#pragma unroll
      for (int mf=0; mf<4; ++mf)
#pragma unroll
        for (int nf=0; nf<4; ++nf)
          acc[mf][nf] = __builtin_amdgcn_mfma_f32_16x16x32_bf16(af[mf], bfv[nf], acc[mf][nf], 0,0,0);
    }
    __syncthreads();
  }

  if (MODE == 1){
    short* oT = (short*)outp;
#pragma unroll
    for (int mf=0; mf<4; ++mf){
      int r0 = m0 + wm*64 + mf*16 + ((l>>4)<<2);
      int s = r0 >> 5, b0 = r0 & 31;
#pragma unroll
      for (int nf=0; nf<4; ++nf){
        int col = n0 + wn*64 + nf*16 + (l&15);
        float bv = bias ? bias[col] : 0.f;
        short tmp[4];
#pragma unroll
        for (int j=0;j<4;++j) tmp[j] = f2bf(acc[mf][nf][j] + bv);
        *(i32x2*)(oT + ((size_t)s*Ntot + col)*32 + b0) = *(i32x2*)tmp;
      }
    }
  } else if (MODE == 3){
    short* o = (short*)outp;
#pragma unroll
    for (int mf=0; mf<4; ++mf){
      int r0 = m0 + wm*64 + mf*16 + ((l>>4)<<2);
#pragma unroll
      for (int nf=0; nf<4; ++nf){
        int col = n0 + wn*64 + nf*16 + (l&15);
        if (col < Nreal){
          float bv = bias ? bias[col] : 0.f;
#pragma unroll
          for (int j=0;j<4;++j) o[(size_t)(r0+j)*Nreal + col] = f2bf(acc[mf][nf][j] + bv);
        }
      }
    }
  } else { // MODE 4
    short* o = (short*)outp;
#pragma unroll
    for (int mf=0; mf<4; ++mf){
      int r0 = m0 + wm*64 + mf*16 + ((l>>4)<<2);
#pragma unroll
      for (int nf=0; nf<4; ++nf){
        int col = n0 + wn*64 + nf*16 + (l&15);
        float bv = (col < Nreal) ? bias[col] : 0.f;
#pragma unroll
        for (int j=0;j<4;++j) o[(size_t)(r0+j)*Ntot + col] = f2bf(acc[mf][nf][j] + bv);
      }
    }
  }
}

// ---------------- encoder scan: XCD team of 32 (single elected team) ----------------
// band: u32 [2 dir][2 slot][32 b][512 k], word = (bf16 h << 16) | step_tag
__global__ __launch_bounds__(512,4) void enc_scan(
  const short* __restrict__ gxfT, const short* __restrict__ gxbT,
  const short* __restrict__ WhfT, const short* __restrict__ WhbT,
  const float* __restrict__ brf, const float* __restrict__ brb,
  u32* __restrict__ band, float* __restrict__ hfin,
  short* __restrict__ encT, u32* __restrict__ tctr)
{
  const int tid = threadIdx.x;
  int role = team_role(tctr, 32u, gridDim.x);
  if (role < 0) return;

  __shared__ __align__(16) char Asb[32*1024];
  __shared__ float accL[96][36];
  __shared__ float brL[96];
  const int dir = role >> 4, j = role & 15;
  const short* gxT = dir ? gxbT : gxfT;
  const short* WT  = dir ? WhbT : WhfT;
  const float* br  = dir ? brb  : brf;
  u32* bd = band + (size_t)dir*32768;
  const int l = tid & 63, wv = tid >> 6;

  if (tid < 96) brL[tid] = br[(tid>>5)*512 + j*32 + (tid&31)];

  bf16x8 bfr[2][16];
  if (wv < 3){
#pragma unroll
    for (int p=0;p<2;++p){
      int gcol = wv*512 + j*32 + p*16 + (l&15);
      const short* bp = WT + (size_t)gcol*512 + ((l>>4)<<3);
#pragma unroll
      for (int kt=0; kt<16; ++kt) bfr[p][kt] = *(const bf16x8*)(bp + kt*32);
    }
  }

  const int pb = tid & 31, php = tid >> 5;       // publish mapping
  const int sb = tid >> 4, sk0 = (tid & 15)*32;  // stage mapping
  float hreg[2] = {0.f, 0.f};

  for (int t=0; t<128; ++t){
    const int s = dir ? (127-t) : t;
    // stage h_t: dual-path tagged poll (sc0 fast, agent fallback)
    {
      const u32* src = bd + (size_t)(t&1)*16384 + sb*512 + sk0;
      u32 w[32];
      int it = 0;
      for (;;){
        if ((it & 7) == 7){
#pragma unroll
          for (int i=0;i<32;++i) w[i] = cohl4(src+i);
        } else {
          l2ld4x8(src, (i32x4*)w);
        }
        u32 bad = 0;
#pragma unroll
        for (int i=0;i<32;++i) bad |= (w[i] ^ (u32)t) & 0xffffu;
        if (!bad) break;
        ++it;
      }
#pragma unroll
      for (int i=0;i<16;++i){
        u32 p = (w[2*i]>>16) | (w[2*i+1] & 0xffff0000u);
        *(u32*)(Asb + (((u32)(sb*1024 + (sk0+2*i)*2)) ^ ((u32)(sb&15)<<4))) = p;
      }
    }
    __syncthreads();
    if (wv < 3){
      f32x4 acc[2][2];
#pragma unroll
      for (int m=0;m<2;++m){ acc[m][0]=(f32x4){0,0,0,0}; acc[m][1]=(f32x4){0,0,0,0}; }
#pragma unroll
      for (int kt=0; kt<16; ++kt){
#pragma unroll
        for (int m=0;m<2;++m){
          int row = m*16 + (l&15);
          int kbyte = (kt*4 + (l>>4))*16;
          bf16x8 af = *(const bf16x8*)(Asb + (((u32)(row*1024 + kbyte)) ^ ((u32)(row&15)<<4)));
          acc[m][0] = __builtin_amdgcn_mfma_f32_16x16x32_bf16(af, bfr[0][kt], acc[m][0], 0,0,0);
          acc[m][1] = __builtin_amdgcn_mfma_f32_16x16x32_bf16(af, bfr[1][kt], acc[m][1], 0,0,0);
        }
      }
#pragma unroll
      for (int m=0;m<2;++m)
#pragma unroll
        for (int p=0;p<2;++p)
          *(f32x4*)&accL[wv*32 + p*16 + (l&15)][m*16 + ((l>>4)<<2)] = acc[m][p];
    }
    __syncthreads();
    // pointwise + immediate dual tagged publish
    short obf[2];
    {
      int b = pb, hc0 = php*2;
#pragma unroll
      for (int q=0;q<2;++q){
        int hc = hc0 + q, hcol = j*32 + hc;
        float xz = bf2f(gxT[((size_t)s*1536 + hcol)*32 + b]);
        float xr = bf2f(gxT[((size_t)s*1536 + 512 + hcol)*32 + b]);
        float xh = bf2f(gxT[((size_t)s*1536 + 1024 + hcol)*32 + b]);
        float gz = accL[hc][b]    + brL[hc];
        float gr = accL[32+hc][b] + brL[32+hc];
        float gh = accL[64+hc][b] + brL[64+hc];
        float z = sig_p(xz + gz);
        float r = sig_p(xr + gr);
        float hcand = tanhf(xh + r*gh);
        float hn = z*hreg[q] + (1.f-z)*hcand;
        hreg[q] = hn;
        obf[q] = f2bf(hn);
      }
      u32 w0 = ((u32)(unsigned short)obf[0]<<16) | (u32)(t+1);
      u32 w1 = ((u32)(unsigned short)obf[1]<<16) | (u32)(t+1);
      u64 pv = ((u64)w1<<32)|(u64)w0;
      void* dst = bd + (size_t)((t+1)&1)*16384 + pb*512 + j*32 + php*2;
      l2st8(dst, pv);
      cohs8(dst, pv);
    }
    // off-critical-path stores
    {
      int b = pb, hc0 = php*2;
      encT[((size_t)s*1024 + dir*512 + (j*32+hc0))*32 + b]   = obf[0];
      encT[((size_t)s*1024 + dir*512 + (j*32+hc0+1))*32 + b] = obf[1];
      if (dir && t == 127){
        hfin[(j*32+hc0)*32 + b]   = hreg[0];
        hfin[(j*32+hc0+1)*32 + b] = hreg[1];
      }
    }
    __syncthreads();   // protect Asb reuse
  }
}

// ---------------- decoder init: tagged slot0 from hfin (tag 0) ----------------
__global__ void dec_init(const float* __restrict__ hfin, u32* __restrict__ band){
  int i = blockIdx.x*256 + threadIdx.x;   // 16384 = 32 b x 512 k
  int b = i >> 9, k = i & 511;
  band[b*512 + k] = ((u32)(unsigned short)f2bf(hfin[(size_t)k*32 + b])<<16);
}

// ---------------- decoder scan: XCD team of 48 (single elected team) ----------------
// role 0..15 : gh WG j: poll h_t -> MFMA (M=32 via 2 tiles) -> tagged GHt words
// role 16..47: attn+GRU WG b: attention + pointwise, owns h[b] in LDS
__global__ __launch_bounds__(512,4) void dec_scan(
  const short* __restrict__ gxeR,   // [(t*32+b)][1536] bf16 (incl bi_d)
  const short* __restrict__ encx,   // [b][1536][128] bf16
  const short* __restrict__ WhdT,   // [1536][512] bf16
  const float* __restrict__ brd,
  const short* __restrict__ Wa, const short* __restrict__ Uenc, const float* __restrict__ Va,
  const float* __restrict__ hfin,   // [512][32] f32
  u32* __restrict__ hband, u32* __restrict__ GHt,
  short* __restrict__ decRow, u32* __restrict__ tctr)
{
  const int tid = threadIdx.x;
  int role = team_role(tctr, 48u, gridDim.x);
  if (role < 0) return;

  // gh-WG shared
  __shared__ __align__(16) char Asb[32*1024];
  // attn-WG shared
  __shared__ float hs[512];
  __shared__ float gxc[1536];
  __shared__ float brA[1536];
  __shared__ float whp[128*5];
  __shared__ float whv[128];
  __shared__ float scp[128*5];
  __shared__ float sc[128];
  __shared__ float red[4];
  __shared__ float vL[128];
  __shared__ float aL[128];

  const int l = tid & 63, wv = tid >> 6;

  if (role < 16){
    // ---- gh WG j: 6 waves x one 16-col n-tile x TWO 16-batch m-tiles ----
    const int j = role;
    const int colbase = (wv>>1)*512 + j*32 + ((wv&1)<<4);   // valid for wv<6
    bf16x8 bfr[16];
    if (wv < 6){
      const short* bp = WhdT + (size_t)(colbase + (l&15))*512 + ((l>>4)<<3);
#pragma unroll
      for (int kt=0; kt<16; ++kt) bfr[kt] = *(const bf16x8*)(bp + kt*32);
    }
    const int sb = tid >> 4, sk0 = (tid & 15)*32;
    for (int t=0; t<128; ++t){
      // stage h_t: dual-path tagged poll
      {
        const u32* src = hband + (size_t)(t&1)*16384 + sb*512 + sk0;
        u32 w[32];
        int it = 0;
        for (;;){
          if ((it & 7) == 7){
#pragma unroll
            for (int i=0;i<32;++i) w[i] = cohl4(src+i);
          } else {
            l2ld4x8(src, (i32x4*)w);
          }
          u32 bad = 0;
#pragma unroll
          for (int i=0;i<32;++i) bad |= (w[i] ^ (u32)t) & 0xffffu;
          if (!bad) break;
          ++it;
        }
#pragma unroll
        for (int i=0;i<16;++i){
          u32 p = (w[2*i]>>16) | (w[2*i+1] & 0xffff0000u);
          *(u32*)(Asb + (((u32)(sb*1024 + (sk0+2*i)*2)) ^ ((u32)(sb&15)<<4))) = p;
        }
      }
      __syncthreads();
      if (wv < 6){
        f32x4 acc0 = (f32x4){0.f,0.f,0.f,0.f};
        f32x4 acc1 = (f32x4){0.f,0.f,0.f,0.f};
#pragma unroll
        for (int kt=0; kt<16; ++kt){
          int kbyte = (kt*32 + ((l>>4)<<3))*2;
          int r0 = l & 15, r1 = 16 + (l & 15);
          bf16x8 af0 = *(const bf16x8*)(Asb + (((u32)(r0*1024 + kbyte)) ^ ((u32)(r0&15)<<4)));
          bf16x8 af1 = *(const bf16x8*)(Asb + (((u32)(r1*1024 + kbyte)) ^ ((u32)(r1&15)<<4)));
          acc0 = __builtin_amdgcn_mfma_f32_16x16x32_bf16(af0, bfr[kt], acc0, 0,0,0);
          acc1 = __builtin_amdgcn_mfma_f32_16x16x32_bf16(af1, bfr[kt], acc1, 0,0,0);
        }
        // dual publish: batch = m*16 + (l>>4)*4 + r, gcol = colbase + (l&15), tag t+1
#pragma unroll
        for (int r=0;r<4;++r){
          u32 wd0 = ((u32)(unsigned short)f2bf(acc0[r])<<16) | (u32)(t+1);
          u32* p0 = &GHt[(size_t)((l>>4)*4 + r)*1536 + colbase + (l&15)];
          l2st(p0, wd0); cohs4(p0, wd0);
          u32 wd1 = ((u32)(unsigned short)f2bf(acc1[r])<<16) | (u32)(t+1);
          u32* p1 = &GHt[(size_t)(16 + (l>>4)*4 + r)*1536 + colbase + (l&15)];
          l2st(p1, wd1); cohs4(p1, wd1);
        }
      }
      __syncthreads();   // protect Asb reuse
    }
  } else {
    // ---- attn+GRU WG, batch b ----
    const int b = role - 16;
    u32 wa[64];
    {
      const u32* wp = (const u32*)(Wa + (size_t)(tid&127)*512 + (tid>>7)*128);
#pragma unroll
      for (int i=0;i<64;++i) wa[i] = wp[i];
    }
    u32 ue[16];
    {
      int s = tid & 127, aq = tid >> 7;
      const u32* up = (const u32*)(Uenc + ((size_t)(s*32 + b))*128 + aq*32);
#pragma unroll
      for (int i=0;i<16;++i) ue[i] = up[i];
    }
    if (tid < 128) vL[tid] = Va[tid];
    for (int i = tid; i < 1536; i += 512) brA[i] = brd[i];
    hs[tid] = hfin[(size_t)tid*32 + b];
    const short* eb = encx + (size_t)b*1536*128;
    __syncthreads();

    for (int t=0; t<128; ++t){
      // wh = h @ Wa^T (k split 4-way)  [h local in LDS]
      {
        int a = tid & 127, kq2 = tid >> 7;
        float p = 0.f;
        const float* hp2 = &hs[kq2*128];
#pragma unroll 8
        for (int i=0;i<64;++i){
          u32 w2 = wa[i];
          float2 h2 = *(const float2*)(hp2 + 2*i);
          p += bf2f((short)(w2 & 0xffff))*h2.x + bf2f((short)(w2 >> 16))*h2.y;
        }
        whp[a*5 + kq2] = p;
      }
      __syncthreads();
      if (tid < 128) whv[tid] = whp[tid*5]+whp[tid*5+1]+whp[tid*5+2]+whp[tid*5+3];
      __syncthreads();
      // score_s = sum_a tanh(wh_a + Uenc) * v_a (a split 4-way)
      {
        int s = tid & 127, aq = tid >> 7;
        float p = 0.f;
#pragma unroll 4
        for (int i=0;i<16;++i){
          u32 u2 = ue[i];
          int a0 = aq*32 + 2*i;
          p += tanh_fast(whv[a0]   + bf2f((short)(u2 & 0xffff))) * vL[a0];
          p += tanh_fast(whv[a0+1] + bf2f((short)(u2 >> 16)))    * vL[a0+1];
        }
        scp[s*5 + aq] = p;
      }
      __syncthreads();
      if (tid < 128) sc[tid] = scp[tid*5]+scp[tid*5+1]+scp[tid*5+2]+scp[tid*5+3];
      __syncthreads();
      float ev = 0.f;
      if (tid < 128){
        float v = sc[tid], mx = v;
#pragma unroll
        for (int d2=32; d2; d2>>=1) mx = fmaxf(mx, __shfl_xor(mx, d2));
        if ((tid & 63) == 0) red[tid>>6] = mx;
      }
      __syncthreads();
      if (tid < 128){
        float mx = fmaxf(red[0], red[1]);
        ev = __expf(sc[tid] - mx);
        float sm = ev;
#pragma unroll
        for (int d2=32; d2; d2>>=1) sm += __shfl_xor(sm, d2);
        if ((tid & 63) == 0) red[2 + (tid>>6)] = sm;
      }
      __syncthreads();
      if (tid < 128) aL[tid] = ev / (red[2] + red[3]);
      __syncthreads();
      // gxctx: 3 cols/thread from L2-resident ENCX slice
      {
        int col = tid*3;
        float a0=0.f, a1=0.f, a2=0.f;
        const short* e0 = eb + (size_t)col*128;
#pragma unroll
        for (int sb2=0; sb2<16; ++sb2){
          f32x4 av0 = *(const f32x4*)&aL[sb2*8];
          f32x4 av1 = *(const f32x4*)&aL[sb2*8+4];
          bf16x8 ev0 = *(const bf16x8*)(e0 + sb2*8);
          bf16x8 ev1 = *(const bf16x8*)(e0 + 128 + sb2*8);
          bf16x8 ev2 = *(const bf16x8*)(e0 + 256 + sb2*8);
#pragma unroll
          for (int i=0;i<4;++i){
            a0 += bf2f(ev0[i])*av0[i]; a1 += bf2f(ev1[i])*av0[i]; a2 += bf2f(ev2[i])*av0[i];
            a0 += bf2f(ev0[4+i])*av1[i]; a1 += bf2f(ev1[4+i])*av1[i]; a2 += bf2f(ev2[4+i])*av1[i];
          }
        }
        gxc[col] = a0; gxc[col+1] = a1; gxc[col+2] = a2;
      }
      __syncthreads();
      // prefetch gx (independent of GH)
      const short* gx = gxeR + ((size_t)t*32 + b)*1536;
      float gx0 = bf2f(gx[tid])        + gxc[tid];
      float gx1 = bf2f(gx[512 + tid])  + gxc[512 + tid];
      float gx2 = bf2f(gx[1024 + tid]) + gxc[1024 + tid];
      // poll own GH words (tag t+1), dual-path; pointwise; dual publish h_{t+1}
      short mybf;
      {
        const u32* gp = GHt + (size_t)b*1536 + tid;
        u32 g[3];
        u32 want = (u32)(t+1);
        int it = 0;
        for (;;){
          if ((it & 7) == 7){ g[0]=cohl4(gp); g[1]=cohl4(gp+512); g[2]=cohl4(gp+1024); }
          else l2ld3(gp, g);
          u32 bad = ((g[0]^want) | (g[1]^want) | (g[2]^want)) & 0xffffu;
          if (!bad) break;
          ++it;
        }
        float gh0 = bf2f((short)(g[0]>>16));
        float gh1 = bf2f((short)(g[1]>>16));
        float gh2 = bf2f((short)(g[2]>>16));
        float z = sig_p(gx0 + gh0 + brA[tid]);
        float r = sig_p(gx1 + gh1 + brA[512 + tid]);
        float hcand = tanhf(gx2 + r*(gh2 + brA[1024 + tid]));
        float hp = hs[tid];
        float hn = z*hp + (1.f-z)*hcand;
        mybf = f2bf(hn);
        u32 wd = ((u32)(unsigned short)mybf<<16) | (u32)(t+1);
        u32* dst = &hband[(size_t)((t+1)&1)*16384 + b*512 + tid];
        l2st(dst, wd); cohs4(dst, wd);
        hs[tid] = hn;
      }
      decRow[((size_t)t*32 + b)*512 + tid] = mybf;   // off critical path
      __syncthreads();                               // hs ready for next wh
    }
  }
}

// ---------------- fused softmax finish: bf16 logits -> normalized f32 ----------------
__global__ __launch_bounds__(256) void soft_finish(
  const short* __restrict__ lg, float* __restrict__ out, int Nreal, int NVP)
{
  int r = blockIdx.x;                 // r = t*32 + b
  int b = r & 31, t = r >> 5;
  const short* row = lg + (size_t)r*NVP;
  float* orow = out + (size_t)(b*128 + t)*Nreal;
  __shared__ float ssum[256];
  float s = 0.f;
  for (int c = threadIdx.x; c < 4000; c += 256){
    bf16x8 v = *(const bf16x8*)(row + c*8);
#pragma unroll
    for (int j=0;j<8;++j) s += __expf(bf2f(v[j]));
  }
  if (threadIdx.x == 0) s += __expf(bf2f(row[32000]));
  ssum[threadIdx.x] = s; __syncthreads();
  for (int d = 128; d; d >>= 1){
    if (threadIdx.x < d) ssum[threadIdx.x] += ssum[threadIdx.x + d];
    __syncthreads();
  }
  float inv = 1.f/ssum[0];
  for (int c = threadIdx.x; c < 4000; c += 256){
    bf16x8 v = *(const bf16x8*)(row + c*8);
    f32x4 o0, o1;
#pragma unroll
    for (int j=0;j<4;++j) o0[j] = __expf(bf2f(v[j]))*inv;
#pragma unroll
    for (int j=0;j<4;++j) o1[j] = __expf(bf2f(v[4+j]))*inv;
    *(f32x4*)(orow + c*8) = o0;
    *(f32x4*)(orow + c*8 + 4) = o1;
  }
  if (threadIdx.x == 0) orow[32000] = __expf(bf2f(row[32000]))*inv;
}

// ---------------- host ----------------
extern "C" void kernel_launch(void* const* d_in, const int* in_sizes, int n_in,
                              void* d_out, int out_size, void* d_ws, size_t ws_size,
                              hipStream_t stream)
{
  const int*   tokens=(const int*)  d_in[0];
  const float* emb  =(const float*)d_in[1];
  const float* Wx_f =(const float*)d_in[2];
  const float* Wh_f =(const float*)d_in[3];
  const float* bi_f =(const float*)d_in[4];
  const float* br_f =(const float*)d_in[5];
  const float* Wx_b =(const float*)d_in[6];
  const float* Wh_b =(const float*)d_in[7];
  const float* bi_b =(const float*)d_in[8];
  const float* br_b =(const float*)d_in[9];
  const float* W_a  =(const float*)d_in[10];
  const float* U_a  =(const float*)d_in[11];
  const float* V_a  =(const float*)d_in[12];
  const float* Wx_d =(const float*)d_in[13];
  const float* Wh_d =(const float*)d_in[14];
  const float* bi_d =(const float*)d_in[15];
  const float* br_d =(const float*)d_in[16];
  const float* Wo   =(const float*)d_in[17];
  const float* bo   =(const float*)d_in[18];

  const int NV = 32001, NVP = 32128, NCB = 251;

  char* base = (char*)d_ws; size_t off = 0;
  auto alloc = [&](size_t bytes)->char*{
    off = (off + 255) & ~(size_t)255;
    char* p = base + off; off += bytes; return p;
  };
  u32*   tctrE  = (u32*)  alloc(1024);
  u32*   tctrD  = (u32*)  alloc(1024);
  u32*   band_e = (u32*)  alloc((size_t)2*2*16384*4);   // [2 dir][2 slot][32][512]
  u32*   band_d = (u32*)  alloc((size_t)2*16384*4);     // [2 slot][32][512]
  u32*   GHt    = (u32*)  alloc((size_t)32*1536*4);     // [32][1536]
  float* hfin   = (float*)alloc((size_t)512*32*4);
  short* X      = (short*)alloc((size_t)4096*256*2);
  short* WxfT   = (short*)alloc((size_t)1536*256*2);
  short* WxbT   = (short*)alloc((size_t)1536*256*2);
  short* WhfT   = (short*)alloc((size_t)1536*512*2);
  short* WhbT   = (short*)alloc((size_t)1536*512*2);
  short* WhdT   = (short*)alloc((size_t)1536*512*2);
  short* WxeT   = (short*)alloc((size_t)1536*1024*2);
  short* WxcT   = (short*)alloc((size_t)1536*1024*2);
  short* WoT    = (short*)alloc((size_t)NVP*512*2);
  short* UaB    = (short*)alloc((size_t)128*1024*2);
  short* WaB    = (short*)alloc((size_t)128*512*2);
  short* gxfT   = (short*)alloc((size_t)128*1536*32*2);
  short* gxbT   = (short*)alloc((size_t)128*1536*32*2);
  short* encT   = (short*)alloc((size_t)128*1024*32*2);
  short* encRow = (short*)alloc((size_t)4096*1024*2);
  short* Uenc   = (short*)alloc((size_t)4096*128*2);
  short* gxeR   = (short*)alloc((size_t)4096*1536*2);
  short* encxT1 = (short*)alloc((size_t)128*1536*32*2);
  short* encx   = (short*)alloc((size_t)32*1536*128*2);
  short* decRow = (short*)alloc((size_t)4096*512*2);
  short* logits = (short*)alloc((size_t)4096*NVP*2);

  hipMemsetAsync(tctrE, 0, 1024, stream);
  hipMemsetAsync(tctrD, 0, 1024, stream);
  hipMemsetAsync(band_e, 0, (size_t)2*2*16384*4, stream);   // slot0 = h0 zeros, tag 0
  hipMemsetAsync(band_d, 0, (size_t)2*16384*4, stream);
  hipMemsetAsync(GHt,    0, (size_t)32*1536*4, stream);

  // weight conversions (all BT = [N][K] bf16)
  tconv<<<dim3(1536/32,256/32),dim3(32,8),0,stream>>>(Wx_f, WxfT, 256, 1536, 1536);
  tconv<<<dim3(1536/32,256/32),dim3(32,8),0,stream>>>(Wx_b, WxbT, 256, 1536, 1536);
  tconv<<<dim3(1536/32,512/32),dim3(32,8),0,stream>>>(Wh_f, WhfT, 512, 1536, 1536);
  tconv<<<dim3(1536/32,512/32),dim3(32,8),0,stream>>>(Wh_b, WhbT, 512, 1536, 1536);
  tconv<<<dim3(1536/32,512/32),dim3(32,8),0,stream>>>(Wh_d, WhdT, 512, 1536, 1536);
  tconv<<<dim3(1536/32,1024/32),dim3(32,8),0,stream>>>(Wx_d,                    WxeT, 1024, 1536, 1536);
  tconv<<<dim3(1536/32,1024/32),dim3(32,8),0,stream>>>(Wx_d+(size_t)1024*1536,  WxcT, 1024, 1536, 1536);
  tconv<<<dim3(NVP/32,512/32),dim3(32,8),0,stream>>>(Wo, WoT, 512, NV, NVP);
  cvt1d<<<(128*512+255)/256,256,0,stream>>>(W_a, WaB, 128*512);
  cvt1d<<<(128*1024+255)/256,256,0,stream>>>(U_a, UaB, 128*1024);

  embed_k<<<4096,256,0,stream>>>(tokens, emb, X);

  gemm_k<1><<<dim3(12,32),256,0,stream>>>(X, WxfT, bi_f, gxfT, nullptr, 1536, 256, 1536);
  gemm_k<1><<<dim3(12,32),256,0,stream>>>(X, WxbT, bi_b, gxbT, nullptr, 1536, 256, 1536);

  enc_scan<<<384,512,0,stream>>>(gxfT, gxbT, WhfT, WhbT, br_f, br_b,
                                 band_e, hfin, encT, tctrE);

  btrans<<<dim3(1024/32,128),dim3(32,8),0,stream>>>(encT, encRow, 1024);

  gemm_k<3><<<dim3(1,32),256,0,stream>>>(encRow, UaB, nullptr, Uenc, nullptr, 128, 1024, 128);
  gemm_k<3><<<dim3(12,32),256,0,stream>>>(encRow, WxeT, bi_d, gxeR, nullptr, 1536, 1024, 1536);
  gemm_k<1><<<dim3(12,32),256,0,stream>>>(encRow, WxcT, nullptr, encxT1, nullptr, 1536, 1024, 1536);
  etrans<<<1536,256,0,stream>>>(encxT1, encx);

  dec_init<<<64,256,0,stream>>>(hfin, band_d);

  dec_scan<<<384,512,0,stream>>>(gxeR, encx, WhdT, br_d, WaB, Uenc, V_a,
                                 hfin, band_d, GHt, decRow, tctrD);

  gemm_k<4><<<dim3(NCB,32),256,0,stream>>>(decRow, WoT, bo, logits, nullptr, NV, 512, NVP);

  soft_finish<<<4096,256,0,stream>>>(logits, (float*)d_out, NV, NVP);
}

// Round 13
// 12236.462 us; speedup vs baseline: 1.2881x; 1.2881x over previous
//
#include <hip/hip_runtime.h>
#include <stdint.h>

typedef unsigned int u32;
typedef unsigned long long u64;
typedef __attribute__((ext_vector_type(8))) short bf16x8;
typedef __attribute__((ext_vector_type(4))) float f32x4;
typedef __attribute__((ext_vector_type(4))) int i32x4;
typedef __attribute__((ext_vector_type(2))) int i32x2;

#define DEV static __device__ __forceinline__

DEV short f2bf(float f){ u32 u=__float_as_uint(f); return (short)((u + 0x7fffu + ((u>>16)&1u))>>16); }
DEV float bf2f(short s){ return __uint_as_float(((u32)(unsigned short)s)<<16); }
DEV float sig_p(float x){ return 1.f/(1.f+expf(-x)); }
DEV float tanh_fast(float x){ float e=__expf(2.f*x); return 1.f-2.f/(e+1.f); }

// agent-scope (LLC) accessors — mirror/insurance path
DEV u32  cohl4(const u32* p){ return __hip_atomic_load(p, __ATOMIC_RELAXED, __HIP_MEMORY_SCOPE_AGENT); }
DEV void cohs4(u32* p, u32 v){ __hip_atomic_store(p, v, __ATOMIC_RELAXED, __HIP_MEMORY_SCOPE_AGENT); }
DEV void cohs8(void* p, u64 v){ __hip_atomic_store((u64*)p, v, __ATOMIC_RELAXED, __HIP_MEMORY_SCOPE_AGENT); }

// intra-XCD L2 accessors (sc0 = L1-bypass, XCD-L2 visible)
DEV void l2st(u32* p, u32 v){
  asm volatile("global_store_dword %0, %1, off sc0" :: "v"(p), "v"(v) : "memory");
}
DEV void l2st8(void* p, u64 v){
  asm volatile("global_store_dwordx2 %0, %1, off sc0" :: "v"(p), "v"(v) : "memory");
}
DEV void l2ld4x8(const u32* p, i32x4* w){
  asm volatile(
    "global_load_dwordx4 %0, %8, off sc0\n\t"
    "global_load_dwordx4 %1, %8, off offset:16 sc0\n\t"
    "global_load_dwordx4 %2, %8, off offset:32 sc0\n\t"
    "global_load_dwordx4 %3, %8, off offset:48 sc0\n\t"
    "global_load_dwordx4 %4, %8, off offset:64 sc0\n\t"
    "global_load_dwordx4 %5, %8, off offset:80 sc0\n\t"
    "global_load_dwordx4 %6, %8, off offset:96 sc0\n\t"
    "global_load_dwordx4 %7, %8, off offset:112 sc0\n\t"
    "s_waitcnt vmcnt(0)"
    : "=&v"(w[0]),"=&v"(w[1]),"=&v"(w[2]),"=&v"(w[3]),
      "=&v"(w[4]),"=&v"(w[5]),"=&v"(w[6]),"=&v"(w[7])
    : "v"(p) : "memory");
}
DEV void l2ld3(const u32* p, u32* g){
  asm volatile(
    "global_load_dword %0, %3, off sc0\n\t"
    "global_load_dword %1, %3, off offset:2048 sc0\n\t"
    "global_load_dword %2, %4, off sc0\n\t"
    "s_waitcnt vmcnt(0)"
    : "=&v"(g[0]), "=&v"(g[1]), "=&v"(g[2])
    : "v"(p), "v"(p + 1024) : "memory");
}

// ---- XCD team formation, single elected team, no full-arrival barrier ----
// tc: [xcd*16] per-XCD count, [144] claim word (0 = none, xcd+1 = winner)
DEV int team_role(u32* tc, u32 need){
  __shared__ int roleS;
  if (threadIdx.x == 0){
    u32 xcd;
    asm volatile("s_getreg_b32 %0, hwreg(HW_REG_XCC_ID)" : "=s"(xcd));
    xcd &= 7u;
    u32 rank = __hip_atomic_fetch_add(&tc[xcd*16], 1u, __ATOMIC_RELAXED, __HIP_MEMORY_SCOPE_AGENT);
    u32 win;
    for (;;){
      win = __hip_atomic_load(&tc[144], __ATOMIC_RELAXED, __HIP_MEMORY_SCOPE_AGENT);
      if (win) break;
      u32 cnt = __hip_atomic_load(&tc[xcd*16], __ATOMIC_RELAXED, __HIP_MEMORY_SCOPE_AGENT);
      if (cnt >= need){
        u32 exp0 = 0u;
        __hip_atomic_compare_exchange_strong(&tc[144], &exp0, xcd+1u,
          __ATOMIC_RELAXED, __ATOMIC_RELAXED, __HIP_MEMORY_SCOPE_AGENT);
      }
      __builtin_amdgcn_s_sleep(2);
    }
    roleS = (win == xcd+1u && rank < need) ? (int)rank : -1;
  }
  __syncthreads();
  return roleS;
}

// ---------------- convert / transpose kernels ----------------

__global__ void cvt1d(const float* __restrict__ in, short* __restrict__ out, int n){
  int i = blockIdx.x*256 + threadIdx.x;
  if (i < n) out[i] = f2bf(in[i]);
}

// in f32 [R][C] -> out bf16 [Cpad][R]
__global__ void tconv(const float* __restrict__ in, short* __restrict__ out, int R, int C, int Cpad){
  __shared__ float t[32][33];
  int tx = threadIdx.x, ty = threadIdx.y;
  int c0 = blockIdx.x*32, r0 = blockIdx.y*32;
#pragma unroll
  for (int j=0;j<4;++j){
    int r = r0 + ty + 8*j, c = c0 + tx;
    t[ty+8*j][tx] = (c < C) ? in[(size_t)r*C + c] : 0.f;
  }
  __syncthreads();
#pragma unroll
  for (int j=0;j<4;++j){
    int oc = c0 + ty + 8*j;
    out[(size_t)oc*R + r0 + tx] = f2bf(t[tx][ty+8*j]);
  }
}

// batched transpose: in bf16 [NB][Dd][32] -> out bf16 [NB*32][Dd]
__global__ void btrans(const short* __restrict__ in, short* __restrict__ out, int Dd){
  __shared__ short t[32][33];
  int tx = threadIdx.x, ty = threadIdx.y;
  int d0 = blockIdx.x*32, s = blockIdx.y;
#pragma unroll
  for (int j=0;j<4;++j)
    t[ty+8*j][tx] = in[((size_t)s*Dd + d0 + ty + 8*j)*32 + tx];
  __syncthreads();
#pragma unroll
  for (int j=0;j<4;++j)
    out[((size_t)(s*32 + ty + 8*j))*Dd + d0 + tx] = t[tx][ty+8*j];
}

// [s][1536][32] -> [b][1536][128]
__global__ void etrans(const short* __restrict__ in, short* __restrict__ out){
  __shared__ short t[128][33];
  int c = blockIdx.x, tid = threadIdx.x;
#pragma unroll
  for (int i=0;i<16;++i){
    int idx = tid + i*256;
    t[idx>>5][idx&31] = in[((size_t)(idx>>5)*1536 + c)*32 + (idx&31)];
  }
  __syncthreads();
#pragma unroll
  for (int i=0;i<16;++i){
    int idx = tid + i*256;
    out[((size_t)(idx>>7)*1536 + c)*128 + (idx&127)] = t[idx&127][idx>>7];
  }
}

__global__ void embed_k(const int* __restrict__ tok, const float* __restrict__ emb, short* __restrict__ X){
  int row = blockIdx.x;               // (s,b)
  int s = row >> 5, b = row & 31;
  int tv = tok[b*128 + s];
  X[(size_t)row*256 + threadIdx.x] = f2bf(emb[(size_t)tv*256 + threadIdx.x]);
}

// ---------------- MFMA GEMM  C = A[M,K] * BT[Npad][K] ----------------
template<int MODE>
__global__ __launch_bounds__(256) void gemm_k(
  const short* __restrict__ A, const short* __restrict__ BT,
  const float* __restrict__ bias, void* __restrict__ outp,
  float* __restrict__ psum, int Nreal, int K, int Ntot)
{
  const int m0 = blockIdx.y * 128, n0 = blockIdx.x * 128;
  const int tid = threadIdx.x, l = tid & 63, wv = tid >> 6;
  const int wm = wv >> 1, wn = wv & 1;
  __shared__ __align__(16) short As[128*64];
  __shared__ __align__(16) short Bs[128*64];
  f32x4 acc[4][4];
#pragma unroll
  for (int i=0;i<4;++i)
#pragma unroll
    for (int j=0;j<4;++j) acc[i][j] = (f32x4){0.f,0.f,0.f,0.f};

  const int nkb = K >> 6;
  for (int kb=0; kb<nkb; ++kb){
#pragma unroll
    for (int i=0;i<4;++i){
      int si = tid + i*256;
      int row = si >> 3, seg = si & 7;
      u32 off = (u32)(row*128 + seg*16) ^ (u32)((row&7)<<4);
      *(i32x4*)((char*)As + off) = *(const i32x4*)(A + (size_t)(m0+row)*K + kb*64 + seg*8);
      *(i32x4*)((char*)Bs + off) = *(const i32x4*)(BT + (size_t)(n0+row)*K + kb*64 + seg*8);
    }
    __syncthreads();
#pragma unroll
    for (int kt=0; kt<2; ++kt){
      bf16x8 af[4], bfv[4];
      int seg = kt*4 + (l>>4);
#pragma unroll
      for (int f=0; f<4; ++f){
        int ra = wm*64 + f*16 + (l&15);
        af[f]  = *(const bf16x8*)((char*)As + (((u32)(ra*128 + seg*16)) ^ ((u32)(ra&7)<<4)));
        int rb = wn*64 + f*16 + (l&15);
        bfv[f] = *(const bf16x8*)((char*)Bs + (((u32)(rb*128 + seg*16)) ^ ((u32)(rb&7)<<4)));
      }
#pragma unroll
      for (int mf=0; mf<4; ++mf)
#pragma unroll
        for (int nf=0; nf<4; ++nf)
          acc[mf][nf] = __builtin_amdgcn_mfma_f32_16x16x32_bf16(af[mf], bfv[nf], acc[mf][nf], 0,0,0);
    }
    __syncthreads();
  }

  if (MODE == 1){
    short* oT = (short*)outp;
#pragma unroll
    for (int mf=0; mf<4; ++mf){
      int r0 = m0 + wm*64 + mf*16 + ((l>>4)<<2);
      int s = r0 >> 5, b0 = r0 & 31;
#pragma unroll
      for (int nf=0; nf<4; ++nf){
        int col = n0 + wn*64 + nf*16 + (l&15);
        float bv = bias ? bias[col] : 0.f;
        short tmp[4];
#pragma unroll
        for (int j=0;j<4;++j) tmp[j] = f2bf(acc[mf][nf][j] + bv);
        *(i32x2*)(oT + ((size_t)s*Ntot + col)*32 + b0) = *(i32x2*)tmp;
      }
    }
  } else if (MODE == 3){
    short* o = (short*)outp;
#pragma unroll
    for (int mf=0; mf<4; ++mf){
      int r0 = m0 + wm*64 + mf*16 + ((l>>4)<<2);
#pragma unroll
      for (int nf=0; nf<4; ++nf){
        int col = n0 + wn*64 + nf*16 + (l&15);
        if (col < Nreal){
          float bv = bias ? bias[col] : 0.f;
#pragma unroll
          for (int j=0;j<4;++j) o[(size_t)(r0+j)*Nreal + col] = f2bf(acc[mf][nf][j] + bv);
        }
      }
    }
  } else { // MODE 4
    short* o = (short*)outp;
#pragma unroll
    for (int mf=0; mf<4; ++mf){
      int r0 = m0 + wm*64 + mf*16 + ((l>>4)<<2);
#pragma unroll
      for (int nf=0; nf<4; ++nf){
        int col = n0 + wn*64 + nf*16 + (l&15);
        float bv = (col < Nreal) ? bias[col] : 0.f;
#pragma unroll
        for (int j=0;j<4;++j) o[(size_t)(r0+j)*Ntot + col] = f2bf(acc[mf][nf][j] + bv);
      }
    }
  }
}

// ---------------- encoder scan: XCD team of 32, sc0 primary + mirror insurance ----------------
// band primary: u32 [2 dir][2 slot][32 b][512 k] (65536 words); mirror at +65536
__global__ __launch_bounds__(512,2) void enc_scan(
  const short* __restrict__ gxfT, const short* __restrict__ gxbT,
  const short* __restrict__ WhfT, const short* __restrict__ WhbT,
  const float* __restrict__ brf, const float* __restrict__ brb,
  u32* __restrict__ band, float* __restrict__ hfin,
  short* __restrict__ encT, u32* __restrict__ tctr)
{
  const int tid = threadIdx.x;
  int role = team_role(tctr, 32u);
  if (role < 0) return;

  __shared__ __align__(16) char Asb[32*1024];
  __shared__ float accL[96][36];
  __shared__ float brL[96];
  const int dir = role >> 4, j = role & 15;
  const short* gxT = dir ? gxbT : gxfT;
  const short* WT  = dir ? WhbT : WhfT;
  const float* br  = dir ? brb  : brf;
  u32* bd = band + (size_t)dir*32768;
  const int l = tid & 63, wv = tid >> 6;

  if (tid < 96) brL[tid] = br[(tid>>5)*512 + j*32 + (tid&31)];

  bf16x8 bfr[2][16];
  if (wv < 3){
#pragma unroll
    for (int p=0;p<2;++p){
      int gcol = wv*512 + j*32 + p*16 + (l&15);
      const short* bp = WT + (size_t)gcol*512 + ((l>>4)<<3);
#pragma unroll
      for (int kt=0; kt<16; ++kt) bfr[p][kt] = *(const bf16x8*)(bp + kt*32);
    }
  }

  const int pb = tid & 31, php = tid >> 5;       // publish mapping
  const int sb = tid >> 4, sk0 = (tid & 15)*32;  // stage mapping
  float hreg[2] = {0.f, 0.f};

  for (int t=0; t<128; ++t){
    const int s = dir ? (127-t) : t;
    // stage h_t: sc0 poll, mirror fallback every 32nd iter
    {
      const u32* src  = bd + (size_t)(t&1)*16384 + sb*512 + sk0;
      const u32* srcm = src + 65536;
      u32 w[32];
      int it = 0;
      for (;;){
        if ((it & 31) == 31){
#pragma unroll
          for (int i=0;i<32;++i) w[i] = cohl4(srcm+i);
        } else {
          l2ld4x8(src, (i32x4*)w);
        }
        u32 bad = 0;
#pragma unroll
        for (int i=0;i<32;++i) bad |= (w[i] ^ (u32)t) & 0xffffu;
        if (!bad) break;
        ++it;
      }
#pragma unroll
      for (int i=0;i<16;++i){
        u32 p = (w[2*i]>>16) | (w[2*i+1] & 0xffff0000u);
        *(u32*)(Asb + (((u32)(sb*1024 + (sk0+2*i)*2)) ^ ((u32)(sb&15)<<4))) = p;
      }
    }
    __syncthreads();
    if (wv < 3){
      f32x4 acc[2][2];
#pragma unroll
      for (int m=0;m<2;++m){ acc[m][0]=(f32x4){0,0,0,0}; acc[m][1]=(f32x4){0,0,0,0}; }
#pragma unroll
      for (int kt=0; kt<16; ++kt){
#pragma unroll
        for (int m=0;m<2;++m){
          int row = m*16 + (l&15);
          int kbyte = (kt*4 + (l>>4))*16;
          bf16x8 af = *(const bf16x8*)(Asb + (((u32)(row*1024 + kbyte)) ^ ((u32)(row&15)<<4)));
          acc[m][0] = __builtin_amdgcn_mfma_f32_16x16x32_bf16(af, bfr[0][kt], acc[m][0], 0,0,0);
          acc[m][1] = __builtin_amdgcn_mfma_f32_16x16x32_bf16(af, bfr[1][kt], acc[m][1], 0,0,0);
        }
      }
#pragma unroll
      for (int m=0;m<2;++m)
#pragma unroll
        for (int p=0;p<2;++p)
          *(f32x4*)&accL[wv*32 + p*16 + (l&15)][m*16 + ((l>>4)<<2)] = acc[m][p];
    }
    __syncthreads();
    // pointwise + publish (sc0 primary, agent mirror)
    short obf[2];
    {
      int b = pb, hc0 = php*2;
#pragma unroll
      for (int q=0;q<2;++q){
        int hc = hc0 + q, hcol = j*32 + hc;
        float xz = bf2f(gxT[((size_t)s*1536 + hcol)*32 + b]);
        float xr = bf2f(gxT[((size_t)s*1536 + 512 + hcol)*32 + b]);
        float xh = bf2f(gxT[((size_t)s*1536 + 1024 + hcol)*32 + b]);
        float gz = accL[hc][b]    + brL[hc];
        float gr = accL[32+hc][b] + brL[32+hc];
        float gh = accL[64+hc][b] + brL[64+hc];
        float z = sig_p(xz + gz);
        float r = sig_p(xr + gr);
        float hcand = tanhf(xh + r*gh);
        float hn = z*hreg[q] + (1.f-z)*hcand;
        hreg[q] = hn;
        obf[q] = f2bf(hn);
      }
      u32 w0 = ((u32)(unsigned short)obf[0]<<16) | (u32)(t+1);
      u32 w1 = ((u32)(unsigned short)obf[1]<<16) | (u32)(t+1);
      u64 pv = ((u64)w1<<32)|(u64)w0;
      u32* dst = bd + (size_t)((t+1)&1)*16384 + pb*512 + j*32 + php*2;
      l2st8(dst, pv);
      cohs8(dst + 65536, pv);
    }
    // off-critical-path stores
    {
      int b = pb, hc0 = php*2;
      encT[((size_t)s*1024 + dir*512 + (j*32+hc0))*32 + b]   = obf[0];
      encT[((size_t)s*1024 + dir*512 + (j*32+hc0+1))*32 + b] = obf[1];
      if (dir && t == 127){
        hfin[(j*32+hc0)*32 + b]   = hreg[0];
        hfin[(j*32+hc0+1)*32 + b] = hreg[1];
      }
    }
    __syncthreads();   // protect Asb reuse
  }
}

// ---------------- decoder init: tagged slot0 (tag 0) primary + mirror ----------------
__global__ void dec_init(const float* __restrict__ hfin, u32* __restrict__ band){
  int i = blockIdx.x*256 + threadIdx.x;   // 16384 = 32 b x 512 k
  int b = i >> 9, k = i & 511;
  u32 w = ((u32)(unsigned short)f2bf(hfin[(size_t)k*32 + b])<<16);
  band[b*512 + k] = w;
  band[32768 + b*512 + k] = w;
}

// ---------------- decoder scan: XCD team of 48, sc0 primary + mirror insurance ----------------
// hband primary: u32 [2 slot][32 b][512 k] (32768 words); mirror +32768
// GHt primary:   u32 [32 b][1536 gcol] (49152 words); mirror +49152
__global__ __launch_bounds__(512,4) void dec_scan(
  const short* __restrict__ gxeR,   // [(t*32+b)][1536] bf16 (incl bi_d)
  const short* __restrict__ encx,   // [b][1536][128] bf16
  const short* __restrict__ WhdT,   // [1536][512] bf16
  const float* __restrict__ brd,
  const short* __restrict__ Wa, const short* __restrict__ Uenc, const float* __restrict__ Va,
  const float* __restrict__ hfin,   // [512][32] f32
  u32* __restrict__ hband, u32* __restrict__ GHt,
  short* __restrict__ decRow, u32* __restrict__ tctr)
{
  const int tid = threadIdx.x;
  int role = team_role(tctr, 48u);
  if (role < 0) return;

  // gh-WG shared
  __shared__ __align__(16) char Asb[32*1024];
  // attn-WG shared
  __shared__ float hs[512];
  __shared__ float gxc[1536];
  __shared__ float brA[1536];
  __shared__ float whp[128*5];
  __shared__ float whv[128];
  __shared__ float scp[128*5];
  __shared__ float sc[128];
  __shared__ float red[4];
  __shared__ float vL[128];
  __shared__ float aL[128];

  const int l = tid & 63, wv = tid >> 6;

  if (role < 16){
    // ---- gh WG j: 6 waves x one 16-col n-tile x TWO 16-batch m-tiles ----
    const int j = role;
    const int colbase = (wv>>1)*512 + j*32 + ((wv&1)<<4);   // valid for wv<6
    bf16x8 bfr[16];
    if (wv < 6){
      const short* bp = WhdT + (size_t)(colbase + (l&15))*512 + ((l>>4)<<3);
#pragma unroll
      for (int kt=0; kt<16; ++kt) bfr[kt] = *(const bf16x8*)(bp + kt*32);
    }
    const int sb = tid >> 4, sk0 = (tid & 15)*32;
    for (int t=0; t<128; ++t){
      // stage h_t: sc0 poll, mirror fallback
      {
        const u32* src  = hband + (size_t)(t&1)*16384 + sb*512 + sk0;
        const u32* srcm = src + 32768;
        u32 w[32];
        int it = 0;
        for (;;){
          if ((it & 31) == 31){
#pragma unroll
            for (int i=0;i<32;++i) w[i] = cohl4(srcm+i);
          } else {
            l2ld4x8(src, (i32x4*)w);
          }
          u32 bad = 0;
#pragma unroll
          for (int i=0;i<32;++i) bad |= (w[i] ^ (u32)t) & 0xffffu;
          if (!bad) break;
          ++it;
        }
#pragma unroll
        for (int i=0;i<16;++i){
          u32 p = (w[2*i]>>16) | (w[2*i+1] & 0xffff0000u);
          *(u32*)(Asb + (((u32)(sb*1024 + (sk0+2*i)*2)) ^ ((u32)(sb&15)<<4))) = p;
        }
      }
      __syncthreads();
      if (wv < 6){
        f32x4 acc0 = (f32x4){0.f,0.f,0.f,0.f};
        f32x4 acc1 = (f32x4){0.f,0.f,0.f,0.f};
#pragma unroll
        for (int kt=0; kt<16; ++kt){
          int kbyte = (kt*32 + ((l>>4)<<3))*2;
          int r0 = l & 15, r1 = 16 + (l & 15);
          bf16x8 af0 = *(const bf16x8*)(Asb + (((u32)(r0*1024 + kbyte)) ^ ((u32)(r0&15)<<4)));
          bf16x8 af1 = *(const bf16x8*)(Asb + (((u32)(r1*1024 + kbyte)) ^ ((u32)(r1&15)<<4)));
          acc0 = __builtin_amdgcn_mfma_f32_16x16x32_bf16(af0, bfr[kt], acc0, 0,0,0);
          acc1 = __builtin_amdgcn_mfma_f32_16x16x32_bf16(af1, bfr[kt], acc1, 0,0,0);
        }
        // publish: sc0 primary + agent mirror; batch=(m*16+(l>>4)*4+r), gcol=colbase+(l&15)
#pragma unroll
        for (int r=0;r<4;++r){
          u32 wd0 = ((u32)(unsigned short)f2bf(acc0[r])<<16) | (u32)(t+1);
          u32* p0 = &GHt[(size_t)((l>>4)*4 + r)*1536 + colbase + (l&15)];
          l2st(p0, wd0); cohs4(p0 + 49152, wd0);
          u32 wd1 = ((u32)(unsigned short)f2bf(acc1[r])<<16) | (u32)(t+1);
          u32* p1 = &GHt[(size_t)(16 + (l>>4)*4 + r)*1536 + colbase + (l&15)];
          l2st(p1, wd1); cohs4(p1 + 49152, wd1);
        }
      }
      __syncthreads();   // protect Asb reuse
    }
  } else {
    // ---- attn+GRU WG, batch b ----
    const int b = role - 16;
    u32 wa[64];
    {
      const u32* wp = (const u32*)(Wa + (size_t)(tid&127)*512 + (tid>>7)*128);
#pragma unroll
      for (int i=0;i<64;++i) wa[i] = wp[i];
    }
    u32 ue[16];
    {
      int s = tid & 127, aq = tid >> 7;
      const u32* up = (const u32*)(Uenc + ((size_t)(s*32 + b))*128 + aq*32);
#pragma unroll
      for (int i=0;i<16;++i) ue[i] = up[i];
    }
    if (tid < 128) vL[tid] = Va[tid];
    for (int i = tid; i < 1536; i += 512) brA[i] = brd[i];
    hs[tid] = hfin[(size_t)tid*32 + b];
    const short* eb = encx + (size_t)b*1536*128;
    __syncthreads();

    for (int t=0; t<128; ++t){
      // wh = h @ Wa^T (k split 4-way)  [h local in LDS]
      {
        int a = tid & 127, kq2 = tid >> 7;
        float p = 0.f;
        const float* hp2 = &hs[kq2*128];
#pragma unroll 8
        for (int i=0;i<64;++i){
          u32 w2 = wa[i];
          float2 h2 = *(const float2*)(hp2 + 2*i);
          p += bf2f((short)(w2 & 0xffff))*h2.x + bf2f((short)(w2 >> 16))*h2.y;
        }
        whp[a*5 + kq2] = p;
      }
      __syncthreads();
      if (tid < 128) whv[tid] = whp[tid*5]+whp[tid*5+1]+whp[tid*5+2]+whp[tid*5+3];
      __syncthreads();
      // score_s = sum_a tanh(wh_a + Uenc) * v_a (a split 4-way)
      {
        int s = tid & 127, aq = tid >> 7;
        float p = 0.f;
#pragma unroll 4
        for (int i=0;i<16;++i){
          u32 u2 = ue[i];
          int a0 = aq*32 + 2*i;
          p += tanh_fast(whv[a0]   + bf2f((short)(u2 & 0xffff))) * vL[a0];
          p += tanh_fast(whv[a0+1] + bf2f((short)(u2 >> 16)))    * vL[a0+1];
        }
        scp[s*5 + aq] = p;
      }
      __syncthreads();
      if (tid < 128) sc[tid] = scp[tid*5]+scp[tid*5+1]+scp[tid*5+2]+scp[tid*5+3];
      __syncthreads();
      float ev = 0.f;
      if (tid < 128){
        float v = sc[tid], mx = v;
#pragma unroll
        for (int d2=32; d2; d2>>=1) mx = fmaxf(mx, __shfl_xor(mx, d2));
        if ((tid & 63) == 0) red[tid>>6] = mx;
      }
      __syncthreads();
      if (tid < 128){
        float mx = fmaxf(red[0], red[1]);
        ev = __expf(sc[tid] - mx);
        float sm = ev;
#pragma unroll
        for (int d2=32; d2; d2>>=1) sm += __shfl_xor(sm, d2);
        if ((tid & 63) == 0) red[2 + (tid>>6)] = sm;
      }
      __syncthreads();
      if (tid < 128) aL[tid] = ev / (red[2] + red[3]);
      __syncthreads();
      // gxctx: 3 cols/thread from L2-resident ENCX slice
      {
        int col = tid*3;
        float a0=0.f, a1=0.f, a2=0.f;
        const short* e0 = eb + (size_t)col*128;
#pragma unroll
        for (int sb2=0; sb2<16; ++sb2){
          f32x4 av0 = *(const f32x4*)&aL[sb2*8];
          f32x4 av1 = *(const f32x4*)&aL[sb2*8+4];
          bf16x8 ev0 = *(const bf16x8*)(e0 + sb2*8);
          bf16x8 ev1 = *(const bf16x8*)(e0 + 128 + sb2*8);
          bf16x8 ev2 = *(const bf16x8*)(e0 + 256 + sb2*8);
#pragma unroll
          for (int i=0;i<4;++i){
            a0 += bf2f(ev0[i])*av0[i]; a1 += bf2f(ev1[i])*av0[i]; a2 += bf2f(ev2[i])*av0[i];
            a0 += bf2f(ev0[4+i])*av1[i]; a1 += bf2f(ev1[4+i])*av1[i]; a2 += bf2f(ev2[4+i])*av1[i];
          }
        }
        gxc[col] = a0; gxc[col+1] = a1; gxc[col+2] = a2;
      }
      __syncthreads();
      // prefetch gx (independent of GH)
      const short* gx = gxeR + ((size_t)t*32 + b)*1536;
      float gx0 = bf2f(gx[tid])        + gxc[tid];
      float gx1 = bf2f(gx[512 + tid])  + gxc[512 + tid];
      float gx2 = bf2f(gx[1024 + tid]) + gxc[1024 + tid];
      // poll own GH words (tag t+1): sc0 fast, mirror fallback; pointwise; publish h
      short mybf;
      {
        const u32* gp = GHt + (size_t)b*1536 + tid;
        u32 g[3];
        u32 want = (u32)(t+1);
        int it = 0;
        for (;;){
          if ((it & 31) == 31){
            g[0]=cohl4(gp+49152); g[1]=cohl4(gp+49152+512); g[2]=cohl4(gp+49152+1024);
          } else {
            l2ld3(gp, g);
          }
          u32 bad = ((g[0]^want) | (g[1]^want) | (g[2]^want)) & 0xffffu;
          if (!bad) break;
          ++it;
        }
        float gh0 = bf2f((short)(g[0]>>16));
        float gh1 = bf2f((short)(g[1]>>16));
        float gh2 = bf2f((short)(g[2]>>16));
        float z = sig_p(gx0 + gh0 + brA[tid]);
        float r = sig_p(gx1 + gh1 + brA[512 + tid]);
        float hcand = tanhf(gx2 + r*(gh2 + brA[1024 + tid]));
        float hp = hs[tid];
        float hn = z*hp + (1.f-z)*hcand;
        mybf = f2bf(hn);
        u32 wd = ((u32)(unsigned short)mybf<<16) | (u32)(t+1);
        u32* dst = &hband[(size_t)((t+1)&1)*16384 + b*512 + tid];
        l2st(dst, wd); cohs4(dst + 32768, wd);
        hs[tid] = hn;
      }
      decRow[((size_t)t*32 + b)*512 + tid] = mybf;   // off critical path
      __syncthreads();                               // hs ready for next wh
    }
  }
}

// ---------------- fused softmax finish: bf16 logits -> normalized f32 ----------------
__global__ __launch_bounds__(256) void soft_finish(
  const short* __restrict__ lg, float* __restrict__ out, int Nreal, int NVP)
{
  int r = blockIdx.x;                 // r = t*32 + b
  int b = r & 31, t = r >> 5;
  const short* row = lg + (size_t)r*NVP;
  float* orow = out + (size_t)(b*128 + t)*Nreal;
  __shared__ float ssum[256];
  float s = 0.f;
  for (int c = threadIdx.x; c < 4000; c += 256){
    bf16x8 v = *(const bf16x8*)(row + c*8);
#pragma unroll
    for (int j=0;j<8;++j) s += __expf(bf2f(v[j]));
  }
  if (threadIdx.x == 0) s += __expf(bf2f(row[32000]));
  ssum[threadIdx.x] = s; __syncthreads();
  for (int d = 128; d; d >>= 1){
    if (threadIdx.x < d) ssum[threadIdx.x] += ssum[threadIdx.x + d];
    __syncthreads();
  }
  float inv = 1.f/ssum[0];
  for (int c = threadIdx.x; c < 4000; c += 256){
    bf16x8 v = *(const bf16x8*)(row + c*8);
    f32x4 o0, o1;
#pragma unroll
    for (int j=0;j<4;++j) o0[j] = __expf(bf2f(v[j]))*inv;
#pragma unroll
    for (int j=0;j<4;++j) o1[j] = __expf(bf2f(v[4+j]))*inv;
    *(f32x4*)(orow + c*8) = o0;
    *(f32x4*)(orow + c*8 + 4) = o1;
  }
  if (threadIdx.x == 0) orow[32000] = __expf(bf2f(row[32000]))*inv;
}

// ---------------- host ----------------
extern "C" void kernel_launch(void* const* d_in, const int* in_sizes, int n_in,
                              void* d_out, int out_size, void* d_ws, size_t ws_size,
                              hipStream_t stream)
{
  const int*   tokens=(const int*)  d_in[0];
  const float* emb  =(const float*)d_in[1];
  const float* Wx_f =(const float*)d_in[2];
  const float* Wh_f =(const float*)d_in[3];
  const float* bi_f =(const float*)d_in[4];
  const float* br_f =(const float*)d_in[5];
  const float* Wx_b =(const float*)d_in[6];
  const float* Wh_b =(const float*)d_in[7];
  const float* bi_b =(const float*)d_in[8];
  const float* br_b =(const float*)d_in[9];
  const float* W_a  =(const float*)d_in[10];
  const float* U_a  =(const float*)d_in[11];
  const float* V_a  =(const float*)d_in[12];
  const float* Wx_d =(const float*)d_in[13];
  const float* Wh_d =(const float*)d_in[14];
  const float* bi_d =(const float*)d_in[15];
  const float* br_d =(const float*)d_in[16];
  const float* Wo   =(const float*)d_in[17];
  const float* bo   =(const float*)d_in[18];

  const int NV = 32001, NVP = 32128, NCB = 251;

  char* base = (char*)d_ws; size_t off = 0;
  auto alloc = [&](size_t bytes)->char*{
    off = (off + 255) & ~(size_t)255;
    char* p = base + off; off += bytes; return p;
  };
  u32*   tctrE  = (u32*)  alloc(1024);
  u32*   tctrD  = (u32*)  alloc(1024);
  u32*   band_e = (u32*)  alloc((size_t)2*65536*4);     // primary + mirror
  u32*   band_d = (u32*)  alloc((size_t)2*32768*4);     // primary + mirror
  u32*   GHt    = (u32*)  alloc((size_t)2*49152*4);     // primary + mirror
  float* hfin   = (float*)alloc((size_t)512*32*4);
  short* X      = (short*)alloc((size_t)4096*256*2);
  short* WxfT   = (short*)alloc((size_t)1536*256*2);
  short* WxbT   = (short*)alloc((size_t)1536*256*2);
  short* WhfT   = (short*)alloc((size_t)1536*512*2);
  short* WhbT   = (short*)alloc((size_t)1536*512*2);
  short* WhdT   = (short*)alloc((size_t)1536*512*2);
  short* WxeT   = (short*)alloc((size_t)1536*1024*2);
  short* WxcT   = (short*)alloc((size_t)1536*1024*2);
  short* WoT    = (short*)alloc((size_t)NVP*512*2);
  short* UaB    = (short*)alloc((size_t)128*1024*2);
  short* WaB    = (short*)alloc((size_t)128*512*2);
  short* gxfT   = (short*)alloc((size_t)128*1536*32*2);
  short* gxbT   = (short*)alloc((size_t)128*1536*32*2);
  short* encT   = (short*)alloc((size_t)128*1024*32*2);
  short* encRow = (short*)alloc((size_t)4096*1024*2);
  short* Uenc   = (short*)alloc((size_t)4096*128*2);
  short* gxeR   = (short*)alloc((size_t)4096*1536*2);
  short* encxT1 = (short*)alloc((size_t)128*1536*32*2);
  short* encx   = (short*)alloc((size_t)32*1536*128*2);
  short* decRow = (short*)alloc((size_t)4096*512*2);
  short* logits = (short*)alloc((size_t)4096*NVP*2);

  hipMemsetAsync(tctrE, 0, 1024, stream);
  hipMemsetAsync(tctrD, 0, 1024, stream);
  hipMemsetAsync(band_e, 0, (size_t)2*65536*4, stream);   // slot0 = h0 zeros, tag 0
  hipMemsetAsync(band_d, 0, (size_t)2*32768*4, stream);
  hipMemsetAsync(GHt,    0, (size_t)2*49152*4, stream);

  // weight conversions (all BT = [N][K] bf16)
  tconv<<<dim3(1536/32,256/32),dim3(32,8),0,stream>>>(Wx_f, WxfT, 256, 1536, 1536);
  tconv<<<dim3(1536/32,256/32),dim3(32,8),0,stream>>>(Wx_b, WxbT, 256, 1536, 1536);
  tconv<<<dim3(1536/32,512/32),dim3(32,8),0,stream>>>(Wh_f, WhfT, 512, 1536, 1536);
  tconv<<<dim3(1536/32,512/32),dim3(32,8),0,stream>>>(Wh_b, WhbT, 512, 1536, 1536);
  tconv<<<dim3(1536/32,512/32),dim3(32,8),0,stream>>>(Wh_d, WhdT, 512, 1536, 1536);
  tconv<<<dim3(1536/32,1024/32),dim3(32,8),0,stream>>>(Wx_d,                    WxeT, 1024, 1536, 1536);
  tconv<<<dim3(1536/32,1024/32),dim3(32,8),0,stream>>>(Wx_d+(size_t)1024*1536,  WxcT, 1024, 1536, 1536);
  tconv<<<dim3(NVP/32,512/32),dim3(32,8),0,stream>>>(Wo, WoT, 512, NV, NVP);
  cvt1d<<<(128*512+255)/256,256,0,stream>>>(W_a, WaB, 128*512);
  cvt1d<<<(128*1024+255)/256,256,0,stream>>>(U_a, UaB, 128*1024);

  embed_k<<<4096,256,0,stream>>>(tokens, emb, X);

  gemm_k<1><<<dim3(12,32),256,0,stream>>>(X, WxfT, bi_f, gxfT, nullptr, 1536, 256, 1536);
  gemm_k<1><<<dim3(12,32),256,0,stream>>>(X, WxbT, bi_b, gxbT, nullptr, 1536, 256, 1536);

  enc_scan<<<384,512,0,stream>>>(gxfT, gxbT, WhfT, WhbT, br_f, br_b,
                                 band_e, hfin, encT, tctrE);

  btrans<<<dim3(1024/32,128),dim3(32,8),0,stream>>>(encT, encRow, 1024);

  gemm_k<3><<<dim3(1,32),256,0,stream>>>(encRow, UaB, nullptr, Uenc, nullptr, 128, 1024, 128);
  gemm_k<3><<<dim3(12,32),256,0,stream>>>(encRow, WxeT, bi_d, gxeR, nullptr, 1536, 1024, 1536);
  gemm_k<1><<<dim3(12,32),256,0,stream>>>(encRow, WxcT, nullptr, encxT1, nullptr, 1536, 1024, 1536);
  etrans<<<1536,256,0,stream>>>(encxT1, encx);

  dec_init<<<64,256,0,stream>>>(hfin, band_d);

  dec_scan<<<384,512,0,stream>>>(gxeR, encx, WhdT, br_d, WaB, Uenc, V_a,
                                 hfin, band_d, GHt, decRow, tctrD);

  gemm_k<4><<<dim3(NCB,32),256,0,stream>>>(decRow, WoT, bo, logits, nullptr, NV, 512, NVP);

  soft_finish<<<4096,256,0,stream>>>(logits, (float*)d_out, NV, NVP);
}